// Round 8
// baseline (151.174 us; speedup 1.0000x reference)
//
#include <hip/hip_runtime.h>
#include <float.h>

#define B_   2
#define F_   8192
#define Q_   4096
#define NC   128         // F-chunks
#define FC   (F_/NC)     // 64 triangles per chunk -> 6-bit local index in key
#define PTS  256         // threads per scan block (4 waves)
#define PPT  1           // ONE point per thread: grid 4096 blocks = 2x residency

typedef float f4u __attribute__((ext_vector_type(4), aligned(4)));
typedef unsigned int uint;

// ---------------------------------------------------------------------------
// Exact reference-order Ericson barycentrics. Contract OFF: every op rounds
// exactly like the numpy reference; op order matches term-for-term.
// jnp.select first-true-wins priority; _safe_div(n,d) = n/(d==0?1:d).
__device__ __forceinline__ void bary_uvw(
    float ax, float ay, float az,
    float bx, float by, float bz,
    float cx, float cy, float cz,
    float px, float py, float pz,
    float& u, float& v, float& w)
{
#pragma clang fp contract(off)
    float abx = bx - ax, aby = by - ay, abz = bz - az;
    float acx = cx - ax, acy = cy - ay, acz = cz - az;
    float apx = px - ax, apy = py - ay, apz = pz - az;
    float d1 = abx*apx + aby*apy + abz*apz;
    float d2 = acx*apx + acy*apy + acz*apz;
    float bpx = px - bx, bpy = py - by, bpz = pz - bz;
    float d3 = abx*bpx + aby*bpy + abz*bpz;
    float d4 = acx*bpx + acy*bpy + acz*bpz;
    float qx = px - cx, qy = py - cy, qz = pz - cz;
    float d5 = abx*qx + aby*qy + abz*qz;
    float d6 = acx*qx + acy*qy + acz*qz;
    float vc = d1*d4 - d3*d2;
    float vb = d5*d2 - d1*d6;
    float va = d3*d6 - d5*d4;

    bool c1 = (d1 <= 0.f) && (d2 <= 0.f);
    bool c2 = (d3 >= 0.f) && (d4 <= d3);
    bool c3 = (vc <= 0.f) && (d1 >= 0.f) && (d3 <= 0.f);
    bool c4 = (d6 >= 0.f) && (d5 <= d6);
    bool c5 = (vb <= 0.f) && (d2 >= 0.f) && (d6 <= 0.f);
    bool c6 = (va <= 0.f) && (d4 >= d3) && (d5 >= d6);

    bool e1 = c1;
    bool p1 = !c1;
    bool e2 = p1 && c2;
    bool p2 = p1 && !c2;
    bool e3 = p2 && c3;
    bool p3 = p2 && !c3;
    bool e4 = p3 && c4;
    bool p4 = p3 && !c4;
    bool e5 = p4 && c5;
    bool p5 = p4 && !c5;
    bool e6 = p5 && c6;

    float d43 = d4 - d3;
    float d56 = d5 - d6;
    float n  = e3 ? d1        : (e5 ? d2        : (e6 ? d43         : 1.f));
    float dd = e3 ? (d1 - d3) : (e5 ? (d2 - d6) : (e6 ? (d43 + d56) : (va + vb + vc)));
    dd = (dd == 0.f) ? 1.f : dd;   // _safe_div
    float t = n / dd;

    float vi = vb * t;
    float wi = vc * t;
    u = e1 ? 1.f : (e2 ? 0.f : (e3 ? 1.f - t : (e4 ? 0.f : (e5 ? 1.f - t : (e6 ? 0.f     : 1.f - vi - wi)))));
    v = e1 ? 0.f : (e2 ? 1.f : (e3 ? t       : (e4 ? 0.f : (e5 ? 0.f     : (e6 ? 1.f - t : vi)))));
    w = e1 ? 0.f : (e2 ? 0.f : (e3 ? 0.f     : (e4 ? 1.f : (e5 ? t       : (e6 ? t       : wi)))));
}

// ---------------------------------------------------------------------------
// Precompute: 6 x float4 nomination constants per triangle (96 B):
// C0 = (abx,aby,abz, -ab.a)   C1 = (acx,acy,acz, -ac.a)
// C2 = (-2ax,-2ay,-2az, a.a)  C3 = (daa, dcc, -dac, nn)
// C4 = (1/daa, 1/dcc, 1/dbc, 1/nn)   C5 = (daa-dac, -daa, -dcc, -dbc)
// Negations pre-applied so the asm needs no source modifiers.
__global__ void precompute_kernel(const float* __restrict__ tri,
                                  float4* __restrict__ cons)
{
    int i = blockIdx.x * blockDim.x + threadIdx.x;
    if (i >= B_ * F_) return;
    const float* g = tri + (size_t)i * 9;
    float ax = g[0], ay = g[1], az = g[2];
    float bx = g[3], by = g[4], bz = g[5];
    float cx = g[6], cy = g[7], cz = g[8];
    float abx = bx - ax, aby = by - ay, abz = bz - az;
    float acx = cx - ax, acy = cy - ay, acz = cz - az;
    float daa = abx*abx + aby*aby + abz*abz;
    float dcc = acx*acx + acy*acy + acz*acz;
    float dac = abx*acx + aby*acy + abz*acz;
    float dbc = daa + dcc - 2.f*dac;
    float nn  = daa*dcc - dac*dac;
    float4* o = cons + (size_t)i * 6;
    o[0] = make_float4(abx, aby, abz, -(abx*ax + aby*ay + abz*az));
    o[1] = make_float4(acx, acy, acz, -(acx*ax + acy*ay + acz*az));
    o[2] = make_float4(-2.f*ax, -2.f*ay, -2.f*az, ax*ax + ay*ay + az*az);
    o[3] = make_float4(daa, dcc, -dac, nn);
    o[4] = make_float4(1.f/daa, 1.f/dcc, 1.f/dbc, 1.f/nn);
    o[5] = make_float4(daa - dac, -daa, -dcc, -dbc);
}

// ---------------------------------------------------------------------------
// Nomination key for one (point, triangle): 50 hand-scheduled VALU instrs,
// term-for-term the R4/R6/R7 formula (all passed). Independent chains
// (d1/d2/ap; rab/rac/rbc) round-robined so dependent instrs are >=2 apart.
// d = app - red;  key = bits(d) & ~63 | fl, signed-int top-2 (d >= -eps, so
// signed-int float ordering is valid; tiny negatives sort first, harmless).
__device__ __forceinline__ void eval_key(
    float px, float py, float pz, float pp,
    const f4u C0, const f4u C1, const f4u C2, const f4u C3, const f4u C4,
    const f4u C5, int flv, int im, int& K0, int& K1)
{
    float d1, d2, ap, ins, sg, t1, t2, ts;
    asm("v_mov_b32 %[d1], %[nabA]\n\t"
        "v_mov_b32 %[d2], %[nacA]\n\t"
        "v_mov_b32 %[ap], %[aa]\n\t"
        "v_fmac_f32 %[d1], %[abx], %[px]\n\t"
        "v_fmac_f32 %[d2], %[acx], %[px]\n\t"
        "v_fmac_f32 %[ap], %[n2ax], %[px]\n\t"
        "v_fmac_f32 %[d1], %[aby], %[py]\n\t"
        "v_fmac_f32 %[d2], %[acy], %[py]\n\t"
        "v_fmac_f32 %[ap], %[n2ay], %[py]\n\t"
        "v_fmac_f32 %[d1], %[abz], %[pz]\n\t"
        "v_fmac_f32 %[d2], %[acz], %[pz]\n\t"
        "v_fmac_f32 %[ap], %[n2az], %[pz]\n\t"
        "v_mul_f32 %[t1], %[dcc], %[d1]\n\t"           // t1 = d1*dcc ...
        "v_mul_f32 %[t2], %[daa], %[d2]\n\t"
        "v_add_f32 %[ap], %[pp], %[ap]\n\t"            // app = |p-a|^2
        "v_fmac_f32 %[t1], %[ndac], %[d2]\n\t"         // ... - d2*dac
        "v_fmac_f32 %[t2], %[ndac], %[d1]\n\t"
        "v_add_f32 %[ts], %[t1], %[t2]\n\t"
        "v_mul_f32 %[sg], %[d1], %[t1]\n\t"
        "v_sub_f32 %[ts], %[nn], %[ts]\n\t"            // nn - (t1+t2)
        "v_fmac_f32 %[sg], %[d2], %[t2]\n\t"
        "v_min3_f32 %[ins], %[t1], %[t2], %[ts]\n\t"
        "v_mul_f32 %[sg], %[rnn], %[sg]"               // interior reduction
        : [d1]"=&v"(d1), [d2]"=&v"(d2), [ap]"=&v"(ap), [ins]"=&v"(ins),
          [sg]"=&v"(sg), [t1]"=&v"(t1), [t2]"=&v"(t2), [ts]"=&v"(ts)
        : [px]"v"(px), [py]"v"(py), [pz]"v"(pz), [pp]"v"(pp),
          [abx]"s"(C0.x), [aby]"s"(C0.y), [abz]"s"(C0.z), [nabA]"s"(C0.w),
          [acx]"s"(C1.x), [acy]"s"(C1.y), [acz]"s"(C1.z), [nacA]"s"(C1.w),
          [n2ax]"s"(C2.x), [n2ay]"s"(C2.y), [n2az]"s"(C2.z), [aa]"s"(C2.w),
          [daa]"s"(C3.x), [dcc]"s"(C3.y), [ndac]"s"(C3.z), [nn]"s"(C3.w),
          [rnn]"s"(C4.w));

    float ta, tc, t3, t4, t5, t7, t8;
    unsigned long long mk;
    asm("v_mul_f32 %[ta], %[rdaa], %[d1]\n\t"
        "v_mul_f32 %[tc], %[rdcc], %[d2]\n\t"
        "v_sub_f32 %[t7], %[d2], %[d1]\n\t"
        "v_med3_f32 %[ta], %[ta], 0, 1.0\n\t"          // tab
        "v_med3_f32 %[tc], %[tc], 0, 1.0\n\t"          // tac
        "v_add_f32 %[t7], %[kk], %[t7]\n\t"            // d43
        "v_add_f32 %[t3], %[d1], %[d1]\n\t"            // td1
        "v_add_f32 %[t4], %[d2], %[d2]\n\t"            // td2
        "v_mul_f32 %[t8], %[rdbc], %[t7]\n\t"
        "v_fma_f32 %[t5], %[ndaa], %[ta], %[t3]\n\t"
        "v_fma_f32 %[t4], %[ndcc], %[tc], %[t4]\n\t"
        "v_med3_f32 %[t8], %[t8], 0, 1.0\n\t"          // sbc
        "v_add_f32 %[t7], %[t7], %[t7]\n\t"            // 2*d43
        "v_mul_f32 %[ta], %[ta], %[t5]\n\t"            // rab
        "v_mul_f32 %[tc], %[tc], %[t4]\n\t"            // rac
        "v_fma_f32 %[t7], %[ndbc], %[t8], %[t7]\n\t"
        "v_subrev_f32 %[t3], %[daa], %[t3]\n\t"        // td1 - daa
        "v_mul_f32 %[t7], %[t8], %[t7]\n\t"
        "v_cmp_le_f32 %[mk], 0, %[ins]\n\t"
        "v_add_f32 %[t7], %[t3], %[t7]\n\t"            // rbc
        "v_max3_f32 %[t3], %[ta], %[tc], %[t7]\n\t"    // rmax
        "v_cndmask_b32 %[t3], %[t3], %[sg], %[mk]\n\t" // red
        "v_sub_f32 %[t4], %[ap], %[t3]\n\t"            // d = app - red
        "v_and_or_b32 %[t4], %[t4], %[im], %[flv]\n\t" // key
        "v_max_i32 %[t8], %[K0], %[t4]\n\t"
        "v_min_i32 %[K0], %[K0], %[t4]\n\t"
        "v_min_i32 %[K1], %[K1], %[t8]"
        : [K0]"+v"(K0), [K1]"+v"(K1),
          [ta]"=&v"(ta), [tc]"=&v"(tc), [t3]"=&v"(t3), [t4]"=&v"(t4),
          [t5]"=&v"(t5), [t7]"=&v"(t7), [t8]"=&v"(t8), [mk]"=&s"(mk)
        : [d1]"v"(d1), [d2]"v"(d2), [ins]"v"(ins), [sg]"v"(sg), [ap]"v"(ap),
          [daa]"s"(C3.x), [rdaa]"s"(C4.x), [rdcc]"s"(C4.y), [rdbc]"s"(C4.z),
          [kk]"s"(C5.x), [ndaa]"s"(C5.y), [ndcc]"s"(C5.z), [ndbc]"s"(C5.w),
          [im]"s"(im), [flv]"v"(flv));
}

// ---------------------------------------------------------------------------
// Scan: NO LDS, NO syncthreads. ONE point per thread; grid oversubscribed 2x
// (16384 waves vs 8192 residency) so every SIMD keeps 8 waves and the issue
// ports stay fed. Per-triangle constants via wave-uniform SMEM s_loads,
// software-pipelined one triangle ahead. Inline-asm nomination (count +
// schedule pinned). TAIL exact-evaluates both nominees with the np-order
// contract-off formula reading RAW a,b,c from global tri (bit-identical
// inputs => bit-identical d^2). NO cheap-distance filtering (R5 lesson).
__global__ __launch_bounds__(PTS, 8) void scan_kernel(
    const float* __restrict__ tri, const float* __restrict__ pts,
    const f4u* __restrict__ cons, uint2* __restrict__ keys)
{
    const int im = ~(FC - 1);          // keep key bits; low 6 bits = local face
    const int tid = threadIdx.x;
    const int pb = blockIdx.x, cb = blockIdx.y, bb = blockIdx.z;

    const int q0 = pb * PTS + tid;
    const float* p0 = pts + ((size_t)bb * Q_ + q0) * 3;
    float px0 = p0[0], py0 = p0[1], pz0 = p0[2];
    float pp0 = px0*px0 + py0*py0 + pz0*pz0;

    const f4u* ct = cons + ((size_t)bb * F_ + (size_t)cb * FC) * 6;

    int K00 = 0x7FFFFFFF, K01 = 0x7FFFFFFF;

    // software pipeline: A* holds triangle fl's constants; N* prefetches fl+1
    f4u A0 = ct[0], A1 = ct[1], A2 = ct[2], A3 = ct[3], A4 = ct[4], A5 = ct[5];
    #pragma unroll 2
    for (int fl = 0; fl < FC; ++fl) {
        int nf = (fl + 1 < FC) ? fl + 1 : FC - 1;      // clamp: no OOB read
        const f4u* nt = ct + nf * 6;
        f4u N0 = nt[0], N1 = nt[1], N2 = nt[2], N3 = nt[3], N4 = nt[4], N5 = nt[5];
        eval_key(px0, py0, pz0, pp0, A0, A1, A2, A3, A4, A5, fl, im, K00, K01);
        A0 = N0; A1 = N1; A2 = N2; A3 = N3; A4 = N4; A5 = N5;
    }

    // TAIL: exact np-order eval of both nominees, raw coords from global tri
    // (bit-identical inputs => bit-identical d^2 vs reference).
    {
        float dbest = FLT_MAX; int fbest = 0x7FFFFFFF;
        #pragma unroll
        for (int j = 0; j < 2; ++j) {
            int lf = (j == 0 ? K00 : K01) & (FC - 1);
            const float* tg = tri + ((size_t)bb * F_ + (size_t)cb * FC + lf) * 9;
            f4u ra4 = *(const f4u*)(tg);
            f4u rb4 = *(const f4u*)(tg + 4);
            float rc8 = tg[8];
            float u, v, w;
            bary_uvw(ra4.x, ra4.y, ra4.z, ra4.w, rb4.x, rb4.y,
                     rb4.z, rb4.w, rc8, px0, py0, pz0, u, v, w);
            float d2v;
            {
#pragma clang fp contract(off)
                float cpx = u*ra4.x + v*ra4.w + w*rb4.z;
                float cpy = u*ra4.y + v*rb4.x + w*rb4.w;
                float cpz = u*ra4.z + v*rb4.y + w*rc8;
                float dx = cpx - px0, dy = cpy - py0, dz = cpz - pz0;
                d2v = dx*dx + dy*dy + dz*dz;
            }
            int face = cb * FC + lf;
            if (d2v < dbest || (d2v == dbest && face < fbest)) { dbest = d2v; fbest = face; }
        }
        // point-major [b][q][chunk]: finalize reads coalesced uint4
        keys[((size_t)bb * Q_ + q0) * NC + cb] = make_uint2(__float_as_uint(dbest), (uint)fbest);
    }
}

// ---------------------------------------------------------------------------
// Finalize: one WAVE per point; lane l loads chunks 2l,2l+1 exact pairs
// (coalesced uint4), wave lex-(d,face) reduce == jnp.argmin first occurrence
// (true winner is the exact-min of its chunk's top-2 pair, so it is the
// chunk representative). Lane 0 epilogue, contract-off np-order.
__global__ __launch_bounds__(256) void finalize_kernel(
    const float* __restrict__ tri, const float* __restrict__ pts,
    const float* __restrict__ nrm, const float* __restrict__ cmp,
    const int* __restrict__ faces,
    const uint2* __restrict__ keys,
    float* __restrict__ out)
{
#pragma clang fp contract(off)
    const int lane = threadIdx.x & 63;
    const int t = blockIdx.x * 4 + (threadIdx.x >> 6);
    const int bb = t >> 12;            // Q_ = 4096

    uint4 K = ((const uint4*)keys)[(size_t)t * (NC/2) + lane];
    float dbest = __uint_as_float(K.x); int fbest = (int)K.y;
    float d1v   = __uint_as_float(K.z); int f1v   = (int)K.w;
    if (d1v < dbest || (d1v == dbest && f1v < fbest)) { dbest = d1v; fbest = f1v; }
    for (int off = 32; off > 0; off >>= 1) {
        float od = __shfl_down(dbest, off);
        int   of = __shfl_down(fbest, off);
        if (od < dbest || (od == dbest && of < fbest)) { dbest = od; fbest = of; }
    }
    if (lane != 0) return;

    const float* pp = pts + (size_t)t * 3;
    float px = pp[0], py = pp[1], pz = pp[2];

    const int bestf = fbest;
    const float* tg = tri + ((size_t)bb * F_ + bestf) * 9;
    const float* ng = nrm + ((size_t)bb * F_ + bestf) * 9;
    const float* cg = cmp + ((size_t)bb * F_ + bestf) * 9;
    f4u TA = *(const f4u*)(tg), TB = *(const f4u*)(tg + 4);
    float TC = tg[8];
    f4u NA = *(const f4u*)(ng), NB = *(const f4u*)(ng + 4);
    float NCs = ng[8];
    f4u CA = *(const f4u*)(cg), CB = *(const f4u*)(cg + 4);
    float CC = cg[8];

    float u, v, w;
    bary_uvw(TA.x, TA.y, TA.z, TA.w, TB.x, TB.y, TB.z, TB.w, TC,
             px, py, pz, u, v, w);
    u = fminf(fmaxf(u, 0.f), 1.f);
    v = fminf(fmaxf(v, 0.f), 1.f);
    w = fminf(fmaxf(w, 0.f), 1.f);

    float cpx = u * TA.x + v * TA.w + w * TB.z;
    float cpy = u * TA.y + v * TB.x + w * TB.w;
    float cpz = u * TA.z + v * TB.y + w * TC;
    float nx  = u * NA.x + v * NA.w + w * NB.z;
    float ny  = u * NA.y + v * NB.x + w * NB.w;
    float nz  = u * NA.z + v * NB.y + w * NCs;
    float mx  = u * CA.x + v * CA.w + w * CB.z;
    float my  = u * CA.y + v * CB.x + w * CB.w;
    float mz  = u * CA.z + v * CB.y + w * CC;

    const size_t S3 = (size_t)B_ * Q_ * 3;
    out[(size_t)t * 3 + 0] = cpx - px;
    out[(size_t)t * 3 + 1] = cpy - py;
    out[(size_t)t * 3 + 2] = cpz - pz;
    out[S3 + (size_t)t * 3 + 0] = nx;
    out[S3 + (size_t)t * 3 + 1] = ny;
    out[S3 + (size_t)t * 3 + 2] = nz;
    out[2 * S3 + (size_t)t * 3 + 0] = mx;
    out[2 * S3 + (size_t)t * 3 + 1] = my;
    out[2 * S3 + (size_t)t * 3 + 2] = mz;

    int k = 0; float mm = u;
    if (v > mm) { mm = v; k = 1; }
    if (w > mm) { k = 2; }
    out[3 * S3 + t] = (float)faces[((size_t)bb * F_ + bestf) * 3 + k];
}

extern "C" void kernel_launch(void* const* d_in, const int* in_sizes, int n_in,
                              void* d_out, int out_size, void* d_ws, size_t ws_size,
                              hipStream_t stream) {
    const float* tri   = (const float*)d_in[0];
    const float* pts   = (const float*)d_in[1];
    const float* nrm   = (const float*)d_in[2];
    const float* cmp   = (const float*)d_in[3];
    const int*   faces = (const int*)d_in[4];
    float* out = (float*)d_out;

    uint2*  keys = (uint2*)d_ws;   // [B][Q][NC] exact (d_bits, face) per chunk: 8 MiB
    float4* cons = (float4*)((char*)d_ws + (size_t)B_ * Q_ * NC * sizeof(uint2));  // 1.5 MiB

    precompute_kernel<<<(B_ * F_ + 255) / 256, 256, 0, stream>>>(tri, cons);

    dim3 g1(Q_ / PTS, NC, B_);   // (16, 128, 2) = 4096 blocks x 4 waves = 2x capacity
    scan_kernel<<<g1, PTS, 0, stream>>>(tri, pts, (const f4u*)cons, keys);
    finalize_kernel<<<(B_ * Q_) / 4, 256, 0, stream>>>(
        tri, pts, nrm, cmp, faces, keys, out);
}

// Round 9
// 149.679 us; speedup vs baseline: 1.0100x; 1.0100x over previous
//
#include <hip/hip_runtime.h>
#include <float.h>

#define B_   2
#define F_   8192
#define Q_   4096
#define NC   128         // F-chunks
#define FC   (F_/NC)     // 64 triangles per chunk -> 6-bit local index in key
#define PTS  512         // threads per scan block (8 waves)
#define PPT  2           // points per thread in scan

typedef float f4u __attribute__((ext_vector_type(4), aligned(4)));
typedef float f2u __attribute__((ext_vector_type(2), aligned(8)));
typedef float f2  __attribute__((ext_vector_type(2)));
typedef unsigned int uint;

// ---------------------------------------------------------------------------
// Exact reference-order Ericson barycentrics. Contract OFF: every op rounds
// exactly like the numpy reference; op order matches term-for-term.
// jnp.select first-true-wins priority; _safe_div(n,d) = n/(d==0?1:d).
__device__ __forceinline__ void bary_uvw(
    float ax, float ay, float az,
    float bx, float by, float bz,
    float cx, float cy, float cz,
    float px, float py, float pz,
    float& u, float& v, float& w)
{
#pragma clang fp contract(off)
    float abx = bx - ax, aby = by - ay, abz = bz - az;
    float acx = cx - ax, acy = cy - ay, acz = cz - az;
    float apx = px - ax, apy = py - ay, apz = pz - az;
    float d1 = abx*apx + aby*apy + abz*apz;
    float d2 = acx*apx + acy*apy + acz*apz;
    float bpx = px - bx, bpy = py - by, bpz = pz - bz;
    float d3 = abx*bpx + aby*bpy + abz*bpz;
    float d4 = acx*bpx + acy*bpy + acz*bpz;
    float qx = px - cx, qy = py - cy, qz = pz - cz;
    float d5 = abx*qx + aby*qy + abz*qz;
    float d6 = acx*qx + acy*qy + acz*qz;
    float vc = d1*d4 - d3*d2;
    float vb = d5*d2 - d1*d6;
    float va = d3*d6 - d5*d4;

    bool c1 = (d1 <= 0.f) && (d2 <= 0.f);
    bool c2 = (d3 >= 0.f) && (d4 <= d3);
    bool c3 = (vc <= 0.f) && (d1 >= 0.f) && (d3 <= 0.f);
    bool c4 = (d6 >= 0.f) && (d5 <= d6);
    bool c5 = (vb <= 0.f) && (d2 >= 0.f) && (d6 <= 0.f);
    bool c6 = (va <= 0.f) && (d4 >= d3) && (d5 >= d6);

    bool e1 = c1;
    bool p1 = !c1;
    bool e2 = p1 && c2;
    bool p2 = p1 && !c2;
    bool e3 = p2 && c3;
    bool p3 = p2 && !c3;
    bool e4 = p3 && c4;
    bool p4 = p3 && !c4;
    bool e5 = p4 && c5;
    bool p5 = p4 && !c5;
    bool e6 = p5 && c6;

    float d43 = d4 - d3;
    float d56 = d5 - d6;
    float n  = e3 ? d1        : (e5 ? d2        : (e6 ? d43         : 1.f));
    float dd = e3 ? (d1 - d3) : (e5 ? (d2 - d6) : (e6 ? (d43 + d56) : (va + vb + vc)));
    dd = (dd == 0.f) ? 1.f : dd;   // _safe_div
    float t = n / dd;

    float vi = vb * t;
    float wi = vc * t;
    u = e1 ? 1.f : (e2 ? 0.f : (e3 ? 1.f - t : (e4 ? 0.f : (e5 ? 1.f - t : (e6 ? 0.f     : 1.f - vi - wi)))));
    v = e1 ? 0.f : (e2 ? 1.f : (e3 ? t       : (e4 ? 0.f : (e5 ? 0.f     : (e6 ? 1.f - t : vi)))));
    w = e1 ? 0.f : (e2 ? 0.f : (e3 ? 0.f     : (e4 ? 1.f : (e5 ? t       : (e6 ? t       : wi)))));
}

// ---------------------------------------------------------------------------
// Precompute: PAIR-INTERLEAVED constants. Triangle pair pr = (2pr, 2pr+1),
// 24 f2 fields (48 floats, 192 B/pair = 96 B/tri). Field f of half h at
// float offset pr*48 + 2*f + h. Field map (asm relies on this exactly):
//  0 abx  1 aby  2 abz  3 -ab.a  4 acx  5 acy  6 acz  7 -ac.a
//  8 -2ax 9 -2ay 10 -2az 11 a.a  12 daa 13 dcc 14 -dac 15 nn
// 16 1/daa 17 1/dcc 18 1/dbc 19 1/nn 20 daa-dac 21 -daa 22 -dcc 23 -dbc
__global__ void precompute_kernel(const float* __restrict__ tri,
                                  float* __restrict__ consf)
{
    int i = blockIdx.x * blockDim.x + threadIdx.x;
    if (i >= B_ * F_) return;
    const float* g = tri + (size_t)i * 9;
    float ax = g[0], ay = g[1], az = g[2];
    float bx = g[3], by = g[4], bz = g[5];
    float cx = g[6], cy = g[7], cz = g[8];
    float abx = bx - ax, aby = by - ay, abz = bz - az;
    float acx = cx - ax, acy = cy - ay, acz = cz - az;
    float daa = abx*abx + aby*aby + abz*abz;
    float dcc = acx*acx + acy*acy + acz*acz;
    float dac = abx*acx + aby*acy + abz*acz;
    float dbc = daa + dcc - 2.f*dac;
    float nn  = daa*dcc - dac*dac;
    float* o = consf + (size_t)(i >> 1) * 48 + (i & 1);
    o[0]  = abx;  o[2]  = aby;  o[4]  = abz;  o[6]  = -(abx*ax + aby*ay + abz*az);
    o[8]  = acx;  o[10] = acy;  o[12] = acz;  o[14] = -(acx*ax + acy*ay + acz*az);
    o[16] = -2.f*ax; o[18] = -2.f*ay; o[20] = -2.f*az; o[22] = ax*ax + ay*ay + az*az;
    o[24] = daa;  o[26] = dcc;  o[28] = -dac; o[30] = nn;
    o[32] = 1.f/daa; o[34] = 1.f/dcc; o[36] = 1.f/dbc; o[38] = 1.f/nn;
    o[40] = daa - dac; o[42] = -daa; o[44] = -dcc; o[46] = -dbc;
}

// ---------------------------------------------------------------------------
// FRONT: one point vs a TRIANGLE PAIR -- 22 v_pk_* instrs (each does both
// halves). Per-half arithmetic is op-for-op identical to the verified R6
// scalar sequence (pk_mul/add/fma round per-half exactly like scalar), so
// nomination keys are bit-identical to R6-R8. No VOP3P modifiers; every
// instruction reads at most one SGPR pair. neg1 = {-1,-1} VGPR pair.
__device__ __forceinline__ void eval_front(
    f2 pxx, f2 pyy, f2 pzz, f2 ppp, f2 neg1,
    f2 abx, f2 aby, f2 abz, f2 nabA,
    f2 acx, f2 acy, f2 acz, f2 nacA,
    f2 n2ax, f2 n2ay, f2 n2az, f2 aa,
    f2 daa, f2 dcc, f2 ndac, f2 nn, f2 rnn,
    f2& d1o, f2& d2o, f2& apo, f2& t1o, f2& t2o, f2& tso, f2& sgo)
{
    f2 d1, d2, ap, t1, t2, ts, sg;
    asm("v_pk_mul_f32 %[d1], %[abx], %[pxx]\n\t"
        "v_pk_mul_f32 %[d2], %[acx], %[pxx]\n\t"
        "v_pk_mul_f32 %[ap], %[n2ax], %[pxx]\n\t"
        "v_pk_fma_f32 %[d1], %[aby], %[pyy], %[d1]\n\t"
        "v_pk_fma_f32 %[d2], %[acy], %[pyy], %[d2]\n\t"
        "v_pk_fma_f32 %[ap], %[n2ay], %[pyy], %[ap]\n\t"
        "v_pk_fma_f32 %[d1], %[abz], %[pzz], %[d1]\n\t"
        "v_pk_fma_f32 %[d2], %[acz], %[pzz], %[d2]\n\t"
        "v_pk_fma_f32 %[ap], %[n2az], %[pzz], %[ap]\n\t"
        "v_pk_add_f32 %[d1], %[nabA], %[d1]\n\t"
        "v_pk_add_f32 %[d2], %[nacA], %[d2]\n\t"
        "v_pk_add_f32 %[ap], %[aa], %[ap]\n\t"
        "v_pk_mul_f32 %[t1], %[dcc], %[d1]\n\t"
        "v_pk_mul_f32 %[t2], %[daa], %[d2]\n\t"
        "v_pk_add_f32 %[ap], %[ppp], %[ap]\n\t"        // app = |p-a|^2
        "v_pk_fma_f32 %[t1], %[ndac], %[d2], %[t1]\n\t" // d1*dcc - d2*dac
        "v_pk_fma_f32 %[t2], %[ndac], %[d1], %[t2]\n\t" // d2*daa - d1*dac
        "v_pk_add_f32 %[ts], %[t1], %[t2]\n\t"
        "v_pk_mul_f32 %[sg], %[t1], %[d1]\n\t"
        "v_pk_fma_f32 %[ts], %[ts], %[neg1], %[nn]\n\t" // nn - (t1+t2), exact
        "v_pk_fma_f32 %[sg], %[t2], %[d2], %[sg]\n\t"
        "v_pk_mul_f32 %[sg], %[rnn], %[sg]"             // interior reduction
        : [d1]"=&v"(d1), [d2]"=&v"(d2), [ap]"=&v"(ap), [t1]"=&v"(t1),
          [t2]"=&v"(t2), [ts]"=&v"(ts), [sg]"=&v"(sg)
        : [pxx]"v"(pxx), [pyy]"v"(pyy), [pzz]"v"(pzz), [ppp]"v"(ppp),
          [neg1]"v"(neg1),
          [abx]"s"(abx), [aby]"s"(aby), [abz]"s"(abz), [nabA]"s"(nabA),
          [acx]"s"(acx), [acy]"s"(acy), [acz]"s"(acz), [nacA]"s"(nacA),
          [n2ax]"s"(n2ax), [n2ay]"s"(n2ay), [n2az]"s"(n2az), [aa]"s"(aa),
          [daa]"s"(daa), [dcc]"s"(dcc), [ndac]"s"(ndac), [nn]"s"(nn),
          [rnn]"s"(rnn));
    d1o = d1; d2o = d2; apo = ap; t1o = t1; t2o = t2; tso = ts; sgo = sg;
}

// ---------------------------------------------------------------------------
// BACK: per-half edge/select/key section -- the VERIFIED R6-R8 scalar block
// with v_min3 (ins) folded in. 28 instrs. <=1 SGPR read per instruction.
__device__ __forceinline__ void eval_back(
    float d1, float d2, float t1, float t2, float ts, float sg, float ap,
    float daa, float rdaa, float rdcc, float rdbc,
    float kk, float ndaa, float ndcc, float ndbc,
    int flv, int im, int& K0, int& K1)
{
    float ta, tc, t3, t4, t5, t7, t8, ins;
    unsigned long long mk;
    asm("v_min3_f32 %[ins], %[t1], %[t2], %[ts]\n\t"
        "v_mul_f32 %[ta], %[rdaa], %[d1]\n\t"
        "v_mul_f32 %[tc], %[rdcc], %[d2]\n\t"
        "v_sub_f32 %[t7], %[d2], %[d1]\n\t"
        "v_med3_f32 %[ta], %[ta], 0, 1.0\n\t"          // tab
        "v_med3_f32 %[tc], %[tc], 0, 1.0\n\t"          // tac
        "v_add_f32 %[t7], %[kk], %[t7]\n\t"            // d43
        "v_add_f32 %[t3], %[d1], %[d1]\n\t"            // td1
        "v_add_f32 %[t4], %[d2], %[d2]\n\t"            // td2
        "v_mul_f32 %[t8], %[rdbc], %[t7]\n\t"
        "v_fma_f32 %[t5], %[ndaa], %[ta], %[t3]\n\t"
        "v_fma_f32 %[t4], %[ndcc], %[tc], %[t4]\n\t"
        "v_med3_f32 %[t8], %[t8], 0, 1.0\n\t"          // sbc
        "v_add_f32 %[t7], %[t7], %[t7]\n\t"            // 2*d43
        "v_mul_f32 %[ta], %[ta], %[t5]\n\t"            // rab
        "v_mul_f32 %[tc], %[tc], %[t4]\n\t"            // rac
        "v_fma_f32 %[t7], %[ndbc], %[t8], %[t7]\n\t"
        "v_subrev_f32 %[t3], %[daa], %[t3]\n\t"        // td1 - daa
        "v_mul_f32 %[t7], %[t8], %[t7]\n\t"
        "v_cmp_le_f32 %[mk], 0, %[ins]\n\t"
        "v_add_f32 %[t7], %[t3], %[t7]\n\t"            // rbc
        "v_max3_f32 %[t3], %[ta], %[tc], %[t7]\n\t"    // rmax
        "v_cndmask_b32 %[t3], %[t3], %[sg], %[mk]\n\t" // red
        "v_sub_f32 %[t4], %[ap], %[t3]\n\t"            // d = app - red
        "v_and_or_b32 %[t4], %[t4], %[im], %[flv]\n\t" // key
        "v_max_i32 %[t8], %[K0], %[t4]\n\t"
        "v_min_i32 %[K0], %[K0], %[t4]\n\t"
        "v_min_i32 %[K1], %[K1], %[t8]"
        : [K0]"+v"(K0), [K1]"+v"(K1),
          [ta]"=&v"(ta), [tc]"=&v"(tc), [t3]"=&v"(t3), [t4]"=&v"(t4),
          [t5]"=&v"(t5), [t7]"=&v"(t7), [t8]"=&v"(t8), [ins]"=&v"(ins),
          [mk]"=&s"(mk)
        : [d1]"v"(d1), [d2]"v"(d2), [t1]"v"(t1), [t2]"v"(t2), [ts]"v"(ts),
          [sg]"v"(sg), [ap]"v"(ap),
          [daa]"s"(daa), [rdaa]"s"(rdaa), [rdcc]"s"(rdcc), [rdbc]"s"(rdbc),
          [kk]"s"(kk), [ndaa]"s"(ndaa), [ndcc]"s"(ndcc), [ndbc]"s"(ndbc),
          [im]"s"(im), [flv]"v"(flv));
}

// ---------------------------------------------------------------------------
// Scan: NO LDS, NO syncthreads. Triangle-PAIR loop: pk front (22 instrs / 2
// triangles) + verified scalar back per half. Constants via wave-uniform
// SMEM s_loads from the pair-interleaved table. TAIL exact-evaluates both
// nominees per point with the np-order contract-off formula reading RAW
// a,b,c from global tri (bit-identical inputs => bit-identical d^2).
// NO cheap-distance filtering anywhere (R5 lesson).
__global__ __launch_bounds__(PTS, 4) void scan_kernel(
    const float* __restrict__ tri, const float* __restrict__ pts,
    const float* __restrict__ consf, uint2* __restrict__ keys)
{
    const int im = ~(FC - 1);          // keep key bits; low 6 bits = local face
    const int tid = threadIdx.x;
    const int pb = blockIdx.x, cb = blockIdx.y, bb = blockIdx.z;

    const int q0 = pb * (PTS * PPT) + tid * PPT;
    const float* p0 = pts + ((size_t)bb * Q_ + q0) * 3;    // 24B-aligned (q0 even)
    f2u m0 = *(const f2u*)(p0);
    f2u m1 = *(const f2u*)(p0 + 2);
    f2u m2 = *(const f2u*)(p0 + 4);
    float px0 = m0.x, py0 = m0.y, pz0 = m1.x;
    float px1 = m1.y, py1 = m2.x, pz1 = m2.y;
    float pp0 = px0*px0 + py0*py0 + pz0*pz0;
    float pp1 = px1*px1 + py1*py1 + pz1*pz1;

    // broadcast pairs (built once)
    f2 PX0 = {px0, px0}, PY0 = {py0, py0}, PZ0 = {pz0, pz0}, PP0 = {pp0, pp0};
    f2 PX1 = {px1, px1}, PY1 = {py1, py1}, PZ1 = {pz1, pz1}, PP1 = {pp1, pp1};
    f2 NEG1 = {-1.f, -1.f};

    const float* ctf = consf + (size_t)((bb * F_ + cb * FC) >> 1) * 48;

    int K00 = 0x7FFFFFFF, K01 = 0x7FFFFFFF;
    int K10 = 0x7FFFFFFF, K11 = 0x7FFFFFFF;

    #pragma unroll 2
    for (int j = 0; j < FC/2; ++j) {
        const f4u* cr = (const f4u*)ctf + j * 12;
        f4u r0 = cr[0], r1 = cr[1], r2 = cr[2],  r3 = cr[3];
        f4u r4 = cr[4], r5 = cr[5], r6 = cr[6],  r7 = cr[7];
        f4u r8 = cr[8], r9 = cr[9], r10 = cr[10], r11 = cr[11];
        f2 abx = {r0.x, r0.y},  aby = {r0.z, r0.w};
        f2 abz = {r1.x, r1.y},  nabA = {r1.z, r1.w};
        f2 acx = {r2.x, r2.y},  acy = {r2.z, r2.w};
        f2 acz = {r3.x, r3.y},  nacA = {r3.z, r3.w};
        f2 n2ax = {r4.x, r4.y}, n2ay = {r4.z, r4.w};
        f2 n2az = {r5.x, r5.y}, aa = {r5.z, r5.w};
        f2 daa = {r6.x, r6.y},  dcc = {r6.z, r6.w};
        f2 ndac = {r7.x, r7.y}, nn = {r7.z, r7.w};
        f2 rnn = {r9.z, r9.w};

        int fl0 = 2*j, fl1 = 2*j + 1;
        f2 d1, d2, ap, t1, t2, ts, sg;

        eval_front(PX0, PY0, PZ0, PP0, NEG1, abx, aby, abz, nabA,
                   acx, acy, acz, nacA, n2ax, n2ay, n2az, aa,
                   daa, dcc, ndac, nn, rnn, d1, d2, ap, t1, t2, ts, sg);
        eval_back(d1.x, d2.x, t1.x, t2.x, ts.x, sg.x, ap.x,
                  r6.x, r8.x, r8.z, r9.x, r10.x, r10.z, r11.x, r11.z,
                  fl0, im, K00, K01);
        eval_back(d1.y, d2.y, t1.y, t2.y, ts.y, sg.y, ap.y,
                  r6.y, r8.y, r8.w, r9.y, r10.y, r10.w, r11.y, r11.w,
                  fl1, im, K00, K01);

        eval_front(PX1, PY1, PZ1, PP1, NEG1, abx, aby, abz, nabA,
                   acx, acy, acz, nacA, n2ax, n2ay, n2az, aa,
                   daa, dcc, ndac, nn, rnn, d1, d2, ap, t1, t2, ts, sg);
        eval_back(d1.x, d2.x, t1.x, t2.x, ts.x, sg.x, ap.x,
                  r6.x, r8.x, r8.z, r9.x, r10.x, r10.z, r11.x, r11.z,
                  fl0, im, K10, K11);
        eval_back(d1.y, d2.y, t1.y, t2.y, ts.y, sg.y, ap.y,
                  r6.y, r8.y, r8.w, r9.y, r10.y, r10.w, r11.y, r11.w,
                  fl1, im, K10, K11);
    }

    // TAIL: exact np-order eval of both nominees per point, raw coords from
    // global tri (bit-identical inputs => bit-identical d^2 vs reference).
    float pxs[2] = {px0, px1};
    float pys[2] = {py0, py1};
    float pzs[2] = {pz0, pz1};
    int kk0[2] = {K00, K10};
    int kk1[2] = {K01, K11};

    #pragma unroll
    for (int p = 0; p < 2; ++p) {
        float px = pxs[p], py = pys[p], pz = pzs[p];
        float dbest = FLT_MAX; int fbest = 0x7FFFFFFF;
        #pragma unroll
        for (int j = 0; j < 2; ++j) {
            int lf = (j == 0 ? kk0[p] : kk1[p]) & (FC - 1);
            const float* tg = tri + ((size_t)bb * F_ + (size_t)cb * FC + lf) * 9;
            f4u ra4 = *(const f4u*)(tg);
            f4u rb4 = *(const f4u*)(tg + 4);
            float rc8 = tg[8];
            float u, v, w;
            bary_uvw(ra4.x, ra4.y, ra4.z, ra4.w, rb4.x, rb4.y,
                     rb4.z, rb4.w, rc8, px, py, pz, u, v, w);
            float d2v;
            {
#pragma clang fp contract(off)
                float cpx = u*ra4.x + v*ra4.w + w*rb4.z;
                float cpy = u*ra4.y + v*rb4.x + w*rb4.w;
                float cpz = u*ra4.z + v*rb4.y + w*rc8;
                float dx = cpx - px, dy = cpy - py, dz = cpz - pz;
                d2v = dx*dx + dy*dy + dz*dz;
            }
            int face = cb * FC + lf;
            if (d2v < dbest || (d2v == dbest && face < fbest)) { dbest = d2v; fbest = face; }
        }
        // point-major [b][q][chunk]: finalize reads coalesced uint4
        keys[((size_t)bb * Q_ + q0 + p) * NC + cb] = make_uint2(__float_as_uint(dbest), (uint)fbest);
    }
}

// ---------------------------------------------------------------------------
// Finalize: one WAVE per point; lane l loads chunks 2l,2l+1 exact pairs
// (coalesced uint4), wave lex-(d,face) reduce == jnp.argmin first occurrence
// (true winner is the exact-min of its chunk's top-2 pair, so it is the
// chunk representative). Lane 0 epilogue, contract-off np-order.
__global__ __launch_bounds__(256) void finalize_kernel(
    const float* __restrict__ tri, const float* __restrict__ pts,
    const float* __restrict__ nrm, const float* __restrict__ cmp,
    const int* __restrict__ faces,
    const uint2* __restrict__ keys,
    float* __restrict__ out)
{
#pragma clang fp contract(off)
    const int lane = threadIdx.x & 63;
    const int t = blockIdx.x * 4 + (threadIdx.x >> 6);
    const int bb = t >> 12;            // Q_ = 4096

    uint4 K = ((const uint4*)keys)[(size_t)t * (NC/2) + lane];
    float dbest = __uint_as_float(K.x); int fbest = (int)K.y;
    float d1v   = __uint_as_float(K.z); int f1v   = (int)K.w;
    if (d1v < dbest || (d1v == dbest && f1v < fbest)) { dbest = d1v; fbest = f1v; }
    for (int off = 32; off > 0; off >>= 1) {
        float od = __shfl_down(dbest, off);
        int   of = __shfl_down(fbest, off);
        if (od < dbest || (od == dbest && of < fbest)) { dbest = od; fbest = of; }
    }
    if (lane != 0) return;

    const float* pp = pts + (size_t)t * 3;
    float px = pp[0], py = pp[1], pz = pp[2];

    const int bestf = fbest;
    const float* tg = tri + ((size_t)bb * F_ + bestf) * 9;
    const float* ng = nrm + ((size_t)bb * F_ + bestf) * 9;
    const float* cg = cmp + ((size_t)bb * F_ + bestf) * 9;
    f4u TA = *(const f4u*)(tg), TB = *(const f4u*)(tg + 4);
    float TC = tg[8];
    f4u NA = *(const f4u*)(ng), NB = *(const f4u*)(ng + 4);
    float NCs = ng[8];
    f4u CA = *(const f4u*)(cg), CB = *(const f4u*)(cg + 4);
    float CC = cg[8];

    float u, v, w;
    bary_uvw(TA.x, TA.y, TA.z, TA.w, TB.x, TB.y, TB.z, TB.w, TC,
             px, py, pz, u, v, w);
    u = fminf(fmaxf(u, 0.f), 1.f);
    v = fminf(fmaxf(v, 0.f), 1.f);
    w = fminf(fmaxf(w, 0.f), 1.f);

    float cpx = u * TA.x + v * TA.w + w * TB.z;
    float cpy = u * TA.y + v * TB.x + w * TB.w;
    float cpz = u * TA.z + v * TB.y + w * TC;
    float nx  = u * NA.x + v * NA.w + w * NB.z;
    float ny  = u * NA.y + v * NB.x + w * NB.w;
    float nz  = u * NA.z + v * NB.y + w * NCs;
    float mx  = u * CA.x + v * CA.w + w * CB.z;
    float my  = u * CA.y + v * CB.x + w * CB.w;
    float mz  = u * CA.z + v * CB.y + w * CC;

    const size_t S3 = (size_t)B_ * Q_ * 3;
    out[(size_t)t * 3 + 0] = cpx - px;
    out[(size_t)t * 3 + 1] = cpy - py;
    out[(size_t)t * 3 + 2] = cpz - pz;
    out[S3 + (size_t)t * 3 + 0] = nx;
    out[S3 + (size_t)t * 3 + 1] = ny;
    out[S3 + (size_t)t * 3 + 2] = nz;
    out[2 * S3 + (size_t)t * 3 + 0] = mx;
    out[2 * S3 + (size_t)t * 3 + 1] = my;
    out[2 * S3 + (size_t)t * 3 + 2] = mz;

    int k = 0; float mm = u;
    if (v > mm) { mm = v; k = 1; }
    if (w > mm) { k = 2; }
    out[3 * S3 + t] = (float)faces[((size_t)bb * F_ + bestf) * 3 + k];
}

extern "C" void kernel_launch(void* const* d_in, const int* in_sizes, int n_in,
                              void* d_out, int out_size, void* d_ws, size_t ws_size,
                              hipStream_t stream) {
    const float* tri   = (const float*)d_in[0];
    const float* pts   = (const float*)d_in[1];
    const float* nrm   = (const float*)d_in[2];
    const float* cmp   = (const float*)d_in[3];
    const int*   faces = (const int*)d_in[4];
    float* out = (float*)d_out;

    uint2* keys = (uint2*)d_ws;   // [B][Q][NC] exact (d_bits, face) per chunk: 8 MiB
    float* consf = (float*)((char*)d_ws + (size_t)B_ * Q_ * NC * sizeof(uint2));  // 1.5 MiB

    precompute_kernel<<<(B_ * F_ + 255) / 256, 256, 0, stream>>>(tri, consf);

    dim3 g1(Q_ / (PTS * PPT), NC, B_);   // (4, 128, 2) = 1024 blocks x 8 waves
    scan_kernel<<<g1, PTS, 0, stream>>>(tri, pts, consf, keys);
    finalize_kernel<<<(B_ * Q_) / 4, 256, 0, stream>>>(
        tri, pts, nrm, cmp, faces, keys, out);
}

// Round 10
// 139.774 us; speedup vs baseline: 1.0816x; 1.0709x over previous
//
#include <hip/hip_runtime.h>
#include <float.h>

#define B_   2
#define F_   8192
#define Q_   4096
#define NC   128         // F-chunks
#define FC   (F_/NC)     // 64 triangles per chunk -> 6-bit local index in key
#define PTS  512         // threads per scan block (8 waves)
#define PPT  2           // points per thread in scan

typedef float f4u __attribute__((ext_vector_type(4), aligned(4)));
typedef float f2u __attribute__((ext_vector_type(2), aligned(8)));
typedef unsigned int uint;
typedef unsigned long long u64;

// ---------------------------------------------------------------------------
// Exact reference-order Ericson barycentrics. Contract OFF: every op rounds
// exactly like the numpy reference; op order matches term-for-term.
// jnp.select first-true-wins priority; _safe_div(n,d) = n/(d==0?1:d).
__device__ __forceinline__ void bary_uvw(
    float ax, float ay, float az,
    float bx, float by, float bz,
    float cx, float cy, float cz,
    float px, float py, float pz,
    float& u, float& v, float& w)
{
#pragma clang fp contract(off)
    float abx = bx - ax, aby = by - ay, abz = bz - az;
    float acx = cx - ax, acy = cy - ay, acz = cz - az;
    float apx = px - ax, apy = py - ay, apz = pz - az;
    float d1 = abx*apx + aby*apy + abz*apz;
    float d2 = acx*apx + acy*apy + acz*apz;
    float bpx = px - bx, bpy = py - by, bpz = pz - bz;
    float d3 = abx*bpx + aby*bpy + abz*bpz;
    float d4 = acx*bpx + acy*bpy + acz*bpz;
    float qx = px - cx, qy = py - cy, qz = pz - cz;
    float d5 = abx*qx + aby*qy + abz*qz;
    float d6 = acx*qx + acy*qy + acz*qz;
    float vc = d1*d4 - d3*d2;
    float vb = d5*d2 - d1*d6;
    float va = d3*d6 - d5*d4;

    bool c1 = (d1 <= 0.f) && (d2 <= 0.f);
    bool c2 = (d3 >= 0.f) && (d4 <= d3);
    bool c3 = (vc <= 0.f) && (d1 >= 0.f) && (d3 <= 0.f);
    bool c4 = (d6 >= 0.f) && (d5 <= d6);
    bool c5 = (vb <= 0.f) && (d2 >= 0.f) && (d6 <= 0.f);
    bool c6 = (va <= 0.f) && (d4 >= d3) && (d5 >= d6);

    bool e1 = c1;
    bool p1 = !c1;
    bool e2 = p1 && c2;
    bool p2 = p1 && !c2;
    bool e3 = p2 && c3;
    bool p3 = p2 && !c3;
    bool e4 = p3 && c4;
    bool p4 = p3 && !c4;
    bool e5 = p4 && c5;
    bool p5 = p4 && !c5;
    bool e6 = p5 && c6;

    float d43 = d4 - d3;
    float d56 = d5 - d6;
    float n  = e3 ? d1        : (e5 ? d2        : (e6 ? d43         : 1.f));
    float dd = e3 ? (d1 - d3) : (e5 ? (d2 - d6) : (e6 ? (d43 + d56) : (va + vb + vc)));
    dd = (dd == 0.f) ? 1.f : dd;   // _safe_div
    float t = n / dd;

    float vi = vb * t;
    float wi = vc * t;
    u = e1 ? 1.f : (e2 ? 0.f : (e3 ? 1.f - t : (e4 ? 0.f : (e5 ? 1.f - t : (e6 ? 0.f     : 1.f - vi - wi)))));
    v = e1 ? 0.f : (e2 ? 1.f : (e3 ? t       : (e4 ? 0.f : (e5 ? 0.f     : (e6 ? 1.f - t : vi)))));
    w = e1 ? 0.f : (e2 ? 0.f : (e3 ? 0.f     : (e4 ? 1.f : (e5 ? t       : (e6 ? t       : wi)))));
}

// ---------------------------------------------------------------------------
// Precompute: 6 x float4 nomination constants per triangle (96 B) + fused
// init of the per-point atomic-min table (B*Q u64 <= B*F threads).
// C0 = (abx,aby,abz, -ab.a)   C1 = (acx,acy,acz, -ac.a)
// C2 = (-2ax,-2ay,-2az, a.a)  C3 = (daa, dcc, -dac, nn)
// C4 = (1/daa, 1/dcc, 1/dbc, 1/nn)   C5 = (daa-dac, -daa, -dcc, -dbc)
// Negations pre-applied so the asm needs no source modifiers.
__global__ void precompute_kernel(const float* __restrict__ tri,
                                  float4* __restrict__ cons,
                                  u64* __restrict__ tbl)
{
    int i = blockIdx.x * blockDim.x + threadIdx.x;
    if (i >= B_ * F_) return;
    if (i < B_ * Q_) tbl[i] = ~0ull;           // lex-max sentinel
    const float* g = tri + (size_t)i * 9;
    float ax = g[0], ay = g[1], az = g[2];
    float bx = g[3], by = g[4], bz = g[5];
    float cx = g[6], cy = g[7], cz = g[8];
    float abx = bx - ax, aby = by - ay, abz = bz - az;
    float acx = cx - ax, acy = cy - ay, acz = cz - az;
    float daa = abx*abx + aby*aby + abz*abz;
    float dcc = acx*acx + acy*acy + acz*acz;
    float dac = abx*acx + aby*acy + abz*acz;
    float dbc = daa + dcc - 2.f*dac;
    float nn  = daa*dcc - dac*dac;
    float4* o = cons + (size_t)i * 6;
    o[0] = make_float4(abx, aby, abz, -(abx*ax + aby*ay + abz*az));
    o[1] = make_float4(acx, acy, acz, -(acx*ax + acy*ay + acz*az));
    o[2] = make_float4(-2.f*ax, -2.f*ay, -2.f*az, ax*ax + ay*ay + az*az);
    o[3] = make_float4(daa, dcc, -dac, nn);
    o[4] = make_float4(1.f/daa, 1.f/dcc, 1.f/dbc, 1.f/nn);
    o[5] = make_float4(daa - dac, -daa, -dcc, -dbc);
}

// ---------------------------------------------------------------------------
// Nomination key for one (point, triangle): 50 hand-scheduled VALU instrs,
// term-for-term the R4/R6/R7 formula (all passed). Independent chains
// (d1/d2/ap; rab/rac/rbc) round-robined so dependent instrs are >=2 apart.
// d = app - red;  key = bits(d) & ~63 | fl, signed-int top-2 (d >= -eps, so
// signed-int float ordering is valid; tiny negatives sort first, harmless).
__device__ __forceinline__ void eval_key(
    float px, float py, float pz, float pp,
    const f4u C0, const f4u C1, const f4u C2, const f4u C3, const f4u C4,
    const f4u C5, int flv, int im, int& K0, int& K1)
{
    float d1, d2, ap, ins, sg, t1, t2, ts;
    asm("v_mov_b32 %[d1], %[nabA]\n\t"
        "v_mov_b32 %[d2], %[nacA]\n\t"
        "v_mov_b32 %[ap], %[aa]\n\t"
        "v_fmac_f32 %[d1], %[abx], %[px]\n\t"
        "v_fmac_f32 %[d2], %[acx], %[px]\n\t"
        "v_fmac_f32 %[ap], %[n2ax], %[px]\n\t"
        "v_fmac_f32 %[d1], %[aby], %[py]\n\t"
        "v_fmac_f32 %[d2], %[acy], %[py]\n\t"
        "v_fmac_f32 %[ap], %[n2ay], %[py]\n\t"
        "v_fmac_f32 %[d1], %[abz], %[pz]\n\t"
        "v_fmac_f32 %[d2], %[acz], %[pz]\n\t"
        "v_fmac_f32 %[ap], %[n2az], %[pz]\n\t"
        "v_mul_f32 %[t1], %[dcc], %[d1]\n\t"           // t1 = d1*dcc ...
        "v_mul_f32 %[t2], %[daa], %[d2]\n\t"
        "v_add_f32 %[ap], %[pp], %[ap]\n\t"            // app = |p-a|^2
        "v_fmac_f32 %[t1], %[ndac], %[d2]\n\t"         // ... - d2*dac
        "v_fmac_f32 %[t2], %[ndac], %[d1]\n\t"
        "v_add_f32 %[ts], %[t1], %[t2]\n\t"
        "v_mul_f32 %[sg], %[d1], %[t1]\n\t"
        "v_sub_f32 %[ts], %[nn], %[ts]\n\t"            // nn - (t1+t2)
        "v_fmac_f32 %[sg], %[d2], %[t2]\n\t"
        "v_min3_f32 %[ins], %[t1], %[t2], %[ts]\n\t"
        "v_mul_f32 %[sg], %[rnn], %[sg]"               // interior reduction
        : [d1]"=&v"(d1), [d2]"=&v"(d2), [ap]"=&v"(ap), [ins]"=&v"(ins),
          [sg]"=&v"(sg), [t1]"=&v"(t1), [t2]"=&v"(t2), [ts]"=&v"(ts)
        : [px]"v"(px), [py]"v"(py), [pz]"v"(pz), [pp]"v"(pp),
          [abx]"s"(C0.x), [aby]"s"(C0.y), [abz]"s"(C0.z), [nabA]"s"(C0.w),
          [acx]"s"(C1.x), [acy]"s"(C1.y), [acz]"s"(C1.z), [nacA]"s"(C1.w),
          [n2ax]"s"(C2.x), [n2ay]"s"(C2.y), [n2az]"s"(C2.z), [aa]"s"(C2.w),
          [daa]"s"(C3.x), [dcc]"s"(C3.y), [ndac]"s"(C3.z), [nn]"s"(C3.w),
          [rnn]"s"(C4.w));

    float ta, tc, t3, t4, t5, t7, t8;
    unsigned long long mk;
    asm("v_mul_f32 %[ta], %[rdaa], %[d1]\n\t"
        "v_mul_f32 %[tc], %[rdcc], %[d2]\n\t"
        "v_sub_f32 %[t7], %[d2], %[d1]\n\t"
        "v_med3_f32 %[ta], %[ta], 0, 1.0\n\t"          // tab
        "v_med3_f32 %[tc], %[tc], 0, 1.0\n\t"          // tac
        "v_add_f32 %[t7], %[kk], %[t7]\n\t"            // d43
        "v_add_f32 %[t3], %[d1], %[d1]\n\t"            // td1
        "v_add_f32 %[t4], %[d2], %[d2]\n\t"            // td2
        "v_mul_f32 %[t8], %[rdbc], %[t7]\n\t"
        "v_fma_f32 %[t5], %[ndaa], %[ta], %[t3]\n\t"
        "v_fma_f32 %[t4], %[ndcc], %[tc], %[t4]\n\t"
        "v_med3_f32 %[t8], %[t8], 0, 1.0\n\t"          // sbc
        "v_add_f32 %[t7], %[t7], %[t7]\n\t"            // 2*d43
        "v_mul_f32 %[ta], %[ta], %[t5]\n\t"            // rab
        "v_mul_f32 %[tc], %[tc], %[t4]\n\t"            // rac
        "v_fma_f32 %[t7], %[ndbc], %[t8], %[t7]\n\t"
        "v_subrev_f32 %[t3], %[daa], %[t3]\n\t"        // td1 - daa
        "v_mul_f32 %[t7], %[t8], %[t7]\n\t"
        "v_cmp_le_f32 %[mk], 0, %[ins]\n\t"
        "v_add_f32 %[t7], %[t3], %[t7]\n\t"            // rbc
        "v_max3_f32 %[t3], %[ta], %[tc], %[t7]\n\t"    // rmax
        "v_cndmask_b32 %[t3], %[t3], %[sg], %[mk]\n\t" // red
        "v_sub_f32 %[t4], %[ap], %[t3]\n\t"            // d = app - red
        "v_and_or_b32 %[t4], %[t4], %[im], %[flv]\n\t" // key
        "v_max_i32 %[t8], %[K0], %[t4]\n\t"
        "v_min_i32 %[K0], %[K0], %[t4]\n\t"
        "v_min_i32 %[K1], %[K1], %[t8]"
        : [K0]"+v"(K0), [K1]"+v"(K1),
          [ta]"=&v"(ta), [tc]"=&v"(tc), [t3]"=&v"(t3), [t4]"=&v"(t4),
          [t5]"=&v"(t5), [t7]"=&v"(t7), [t8]"=&v"(t8), [mk]"=&s"(mk)
        : [d1]"v"(d1), [d2]"v"(d2), [ins]"v"(ins), [sg]"v"(sg), [ap]"v"(ap),
          [daa]"s"(C3.x), [rdaa]"s"(C4.x), [rdcc]"s"(C4.y), [rdbc]"s"(C4.z),
          [kk]"s"(C5.x), [ndaa]"s"(C5.y), [ndcc]"s"(C5.z), [ndbc]"s"(C5.w),
          [im]"s"(im), [flv]"v"(flv));
}

// ---------------------------------------------------------------------------
// Scan: R7 champion structure (86.0 us, measured at the VALU-rate bound).
// NO LDS, NO syncthreads; SMEM constants software-pipelined one triangle
// ahead; pinned-asm nomination. TAIL exact-evaluates both nominees with the
// np-order contract-off formula reading RAW a,b,c from global tri
// (bit-identical inputs => bit-identical d^2), then publishes the chunk
// winner via u64 atomicMin( d_bits<<32 | face ) -- lex-(d,face) min across
// chunks == jnp.argmin first occurrence. No keys buffer, no finalize reduce.
__global__ __launch_bounds__(PTS, 8) void scan_kernel(
    const float* __restrict__ tri, const float* __restrict__ pts,
    const f4u* __restrict__ cons, u64* __restrict__ tbl)
{
    const int im = ~(FC - 1);          // keep key bits; low 6 bits = local face
    const int tid = threadIdx.x;
    const int pb = blockIdx.x, cb = blockIdx.y, bb = blockIdx.z;

    const int q0 = pb * (PTS * PPT) + tid * PPT;
    const float* p0 = pts + ((size_t)bb * Q_ + q0) * 3;    // 24B-aligned (q0 even)
    f2u m0 = *(const f2u*)(p0);
    f2u m1 = *(const f2u*)(p0 + 2);
    f2u m2 = *(const f2u*)(p0 + 4);
    float px0 = m0.x, py0 = m0.y, pz0 = m1.x;
    float px1 = m1.y, py1 = m2.x, pz1 = m2.y;
    float pp0 = px0*px0 + py0*py0 + pz0*pz0;
    float pp1 = px1*px1 + py1*py1 + pz1*pz1;

    const f4u* ct = cons + ((size_t)bb * F_ + (size_t)cb * FC) * 6;

    int K00 = 0x7FFFFFFF, K01 = 0x7FFFFFFF;
    int K10 = 0x7FFFFFFF, K11 = 0x7FFFFFFF;

    // software pipeline: A* holds triangle fl's constants; N* prefetches fl+1
    f4u A0 = ct[0], A1 = ct[1], A2 = ct[2], A3 = ct[3], A4 = ct[4], A5 = ct[5];
    #pragma unroll 2
    for (int fl = 0; fl < FC; ++fl) {
        int nf = (fl + 1 < FC) ? fl + 1 : FC - 1;      // clamp: no OOB read
        const f4u* nt = ct + nf * 6;
        f4u N0 = nt[0], N1 = nt[1], N2 = nt[2], N3 = nt[3], N4 = nt[4], N5 = nt[5];
        eval_key(px0, py0, pz0, pp0, A0, A1, A2, A3, A4, A5, fl, im, K00, K01);
        eval_key(px1, py1, pz1, pp1, A0, A1, A2, A3, A4, A5, fl, im, K10, K11);
        A0 = N0; A1 = N1; A2 = N2; A3 = N3; A4 = N4; A5 = N5;
    }

    // TAIL: exact np-order eval of both nominees per point, raw coords from
    // global tri (bit-identical inputs => bit-identical d^2 vs reference).
    float pxs[2] = {px0, px1};
    float pys[2] = {py0, py1};
    float pzs[2] = {pz0, pz1};
    int kk0[2] = {K00, K10};
    int kk1[2] = {K01, K11};

    #pragma unroll
    for (int p = 0; p < 2; ++p) {
        float px = pxs[p], py = pys[p], pz = pzs[p];
        float dbest = FLT_MAX; int fbest = 0x7FFFFFFF;
        #pragma unroll
        for (int j = 0; j < 2; ++j) {
            int lf = (j == 0 ? kk0[p] : kk1[p]) & (FC - 1);
            const float* tg = tri + ((size_t)bb * F_ + (size_t)cb * FC + lf) * 9;
            f4u ra4 = *(const f4u*)(tg);
            f4u rb4 = *(const f4u*)(tg + 4);
            float rc8 = tg[8];
            float u, v, w;
            bary_uvw(ra4.x, ra4.y, ra4.z, ra4.w, rb4.x, rb4.y,
                     rb4.z, rb4.w, rc8, px, py, pz, u, v, w);
            float d2v;
            {
#pragma clang fp contract(off)
                float cpx = u*ra4.x + v*ra4.w + w*rb4.z;
                float cpy = u*ra4.y + v*rb4.x + w*rb4.w;
                float cpz = u*ra4.z + v*rb4.y + w*rc8;
                float dx = cpx - px, dy = cpy - py, dz = cpz - pz;
                d2v = dx*dx + dy*dy + dz*dz;
            }
            int face = cb * FC + lf;
            if (d2v < dbest || (d2v == dbest && face < fbest)) { dbest = d2v; fbest = face; }
        }
        // d2v >= 0 (sum of squares): float bits are unsigned-monotone.
        u64 pk = ((u64)(uint)__float_as_uint(dbest) << 32) | (uint)fbest;
        atomicMin(&tbl[(size_t)bb * Q_ + q0 + p], pk);
    }
}

// ---------------------------------------------------------------------------
// Epilogue: ONE THREAD per point. Reads the global winner from the atomic
// table, recomputes exact barycentrics (contract-off np-order -- identical
// to the old finalize lane-0 body), writes all four outputs.
__global__ void epilogue_kernel(
    const float* __restrict__ tri, const float* __restrict__ pts,
    const float* __restrict__ nrm, const float* __restrict__ cmp,
    const int* __restrict__ faces,
    const u64* __restrict__ tbl,
    float* __restrict__ out)
{
#pragma clang fp contract(off)
    const int t = blockIdx.x * blockDim.x + threadIdx.x;
    if (t >= B_ * Q_) return;
    const int bb = t >> 12;            // Q_ = 4096

    const int bestf = (int)(uint)(tbl[t] & 0xFFFFFFFFu);

    const float* pp = pts + (size_t)t * 3;
    float px = pp[0], py = pp[1], pz = pp[2];

    const float* tg = tri + ((size_t)bb * F_ + bestf) * 9;
    const float* ng = nrm + ((size_t)bb * F_ + bestf) * 9;
    const float* cg = cmp + ((size_t)bb * F_ + bestf) * 9;
    f4u TA = *(const f4u*)(tg), TB = *(const f4u*)(tg + 4);
    float TC = tg[8];
    f4u NA = *(const f4u*)(ng), NB = *(const f4u*)(ng + 4);
    float NCs = ng[8];
    f4u CA = *(const f4u*)(cg), CB = *(const f4u*)(cg + 4);
    float CC = cg[8];

    float u, v, w;
    bary_uvw(TA.x, TA.y, TA.z, TA.w, TB.x, TB.y, TB.z, TB.w, TC,
             px, py, pz, u, v, w);
    u = fminf(fmaxf(u, 0.f), 1.f);
    v = fminf(fmaxf(v, 0.f), 1.f);
    w = fminf(fmaxf(w, 0.f), 1.f);

    float cpx = u * TA.x + v * TA.w + w * TB.z;
    float cpy = u * TA.y + v * TB.x + w * TB.w;
    float cpz = u * TA.z + v * TB.y + w * TC;
    float nx  = u * NA.x + v * NA.w + w * NB.z;
    float ny  = u * NA.y + v * NB.x + w * NB.w;
    float nz  = u * NA.z + v * NB.y + w * NCs;
    float mx  = u * CA.x + v * CA.w + w * CB.z;
    float my  = u * CA.y + v * CB.x + w * CB.w;
    float mz  = u * CA.z + v * CB.y + w * CC;

    const size_t S3 = (size_t)B_ * Q_ * 3;
    out[(size_t)t * 3 + 0] = cpx - px;
    out[(size_t)t * 3 + 1] = cpy - py;
    out[(size_t)t * 3 + 2] = cpz - pz;
    out[S3 + (size_t)t * 3 + 0] = nx;
    out[S3 + (size_t)t * 3 + 1] = ny;
    out[S3 + (size_t)t * 3 + 2] = nz;
    out[2 * S3 + (size_t)t * 3 + 0] = mx;
    out[2 * S3 + (size_t)t * 3 + 1] = my;
    out[2 * S3 + (size_t)t * 3 + 2] = mz;

    int k = 0; float mm = u;
    if (v > mm) { mm = v; k = 1; }
    if (w > mm) { k = 2; }
    out[3 * S3 + t] = (float)faces[((size_t)bb * F_ + bestf) * 3 + k];
}

extern "C" void kernel_launch(void* const* d_in, const int* in_sizes, int n_in,
                              void* d_out, int out_size, void* d_ws, size_t ws_size,
                              hipStream_t stream) {
    const float* tri   = (const float*)d_in[0];
    const float* pts   = (const float*)d_in[1];
    const float* nrm   = (const float*)d_in[2];
    const float* cmp   = (const float*)d_in[3];
    const int*   faces = (const int*)d_in[4];
    float* out = (float*)d_out;

    u64*    tbl  = (u64*)d_ws;                                  // 64 KiB
    float4* cons = (float4*)((char*)d_ws + (size_t)B_ * Q_ * sizeof(u64));  // 1.5 MiB

    precompute_kernel<<<(B_ * F_ + 255) / 256, 256, 0, stream>>>(tri, cons, tbl);

    dim3 g1(Q_ / (PTS * PPT), NC, B_);   // (4, 128, 2) = 1024 blocks x 8 waves
    scan_kernel<<<g1, PTS, 0, stream>>>(tri, pts, (const f4u*)cons, tbl);

    epilogue_kernel<<<(B_ * Q_ + 255) / 256, 256, 0, stream>>>(
        tri, pts, nrm, cmp, faces, tbl, out);
}